// Round 17
// baseline (286.401 us; speedup 1.0000x reference)
//
#include <hip/hip_runtime.h>
#include <hip/hip_cooperative_groups.h>

namespace cg = cooperative_groups;

#define DD 64
#define BSH 7                   // 128 nodes per bucket
#define GBKT 128
#define CAP 2560                // = 10*256; mean fill 2046, +11 sigma
#define MAXBK 800               // >= NBK (782)

// fallback part_k config
#define FTILE 8192
#define FPT 1024
#define FEPT 8
// mega part phase config
#define MTILE 4096
#define MEPT 16

__device__ __forceinline__ float bflo(unsigned int u) {
    return __uint_as_float(u << 16);
}
__device__ __forceinline__ float bfhi(unsigned int u) {
    return __uint_as_float(u & 0xffff0000u);
}
__device__ __forceinline__ unsigned short f2bf(float f) {   // RNE
    unsigned int b = __float_as_uint(f);
    return (unsigned short)((b + 0x7fffu + ((b >> 16) & 1u)) >> 16);
}
__device__ __forceinline__ void acc_row(uint4 r, float4& lo, float4& hi) {
    lo.x += bflo(r.x); lo.y += bfhi(r.x);
    lo.z += bflo(r.y); lo.w += bfhi(r.y);
    hi.x += bflo(r.z); hi.y += bfhi(r.z);
    hi.z += bflo(r.w); hi.w += bfhi(r.w);
}

// ================= gather phase body (shared by mega + fallback) =================
struct SMb {
    int cnt[GBKT]; int excl[GBKT]; int cur[GBKT];
    int sorted[CAP]; int nextn;
};

__device__ __forceinline__ void bg_body(SMb& s, const uint4* __restrict__ ybf,
                                        const int* __restrict__ bp, int count,
                                        const float4* __restrict__ b4,
                                        float4* __restrict__ out4, int N, int k) {
    int tid = threadIdx.x;
    int ebeg = k * CAP;
    int eend = ebeg + count;
    int base = k << BSH;

    if (tid < GBKT) s.cnt[tid] = 0;
    if (tid == 0) s.nextn = 0;
    __syncthreads();
    int ev[10];
    #pragma unroll
    for (int u = 0; u < 10; ++u) {
        int i = ebeg + tid + u * 256;
        ev[u] = (i < eend) ? bp[i] : -1;
    }
    #pragma unroll
    for (int u = 0; u < 10; ++u)
        if (ev[u] >= 0) atomicAdd(&s.cnt[ev[u] & (GBKT - 1)], 1);
    __syncthreads();
    if (tid < GBKT) s.excl[tid] = s.cnt[tid];
    __syncthreads();
    #pragma unroll
    for (int off = 1; off < GBKT; off <<= 1) {
        int t = (tid < GBKT && tid >= off) ? s.excl[tid - off] : 0;
        __syncthreads();
        if (tid < GBKT) s.excl[tid] += t;
        __syncthreads();
    }
    if (tid < GBKT) {
        s.excl[tid] -= s.cnt[tid];
        s.cur[tid] = s.excl[tid];
    }
    __syncthreads();
    #pragma unroll
    for (int u = 0; u < 10; ++u)
        if (ev[u] >= 0) {
            int l = ev[u] & (GBKT - 1);
            int pos = atomicAdd(&s.cur[l], 1);
            s.sorted[pos] = ev[u] >> BSH;
        }
    __syncthreads();

    int lane = tid & 63;
    int c = tid & 7;
    for (;;) {
        int slot;
        if ((tid & 7) == 0) slot = atomicAdd(&s.nextn, 1);
        slot = __shfl(slot, lane & 56, 64);
        if (slot >= GBKT) break;
        int node = base + slot;
        if (node >= N) continue;
        int beg = s.excl[slot];
        int cn = s.cnt[slot];
        int end = beg + cn;
        uint4 v = ybf[(size_t)node * 8 + c];
        float4 a0 = make_float4(bflo(v.x), bfhi(v.x), bflo(v.y), bfhi(v.y));
        float4 a1 = make_float4(bflo(v.z), bfhi(v.z), bflo(v.w), bfhi(v.w));
        float4 e0 = make_float4(0.f, 0.f, 0.f, 0.f);
        float4 e1 = e0;
        int j = beg;
        for (; j + 7 < end; j += 8) {
            int s0 = s.sorted[j],     s1 = s.sorted[j + 1], s2 = s.sorted[j + 2], s3 = s.sorted[j + 3];
            int s4 = s.sorted[j + 4], s5 = s.sorted[j + 5], s6 = s.sorted[j + 6], s7 = s.sorted[j + 7];
            uint4 r0 = ybf[(size_t)s0 * 8 + c];
            uint4 r1 = ybf[(size_t)s1 * 8 + c];
            uint4 r2 = ybf[(size_t)s2 * 8 + c];
            uint4 r3 = ybf[(size_t)s3 * 8 + c];
            uint4 r4 = ybf[(size_t)s4 * 8 + c];
            uint4 r5 = ybf[(size_t)s5 * 8 + c];
            uint4 r6 = ybf[(size_t)s6 * 8 + c];
            uint4 r7 = ybf[(size_t)s7 * 8 + c];
            acc_row(r0, a0, a1);
            acc_row(r1, e0, e1);
            acc_row(r2, a0, a1);
            acc_row(r3, e0, e1);
            acc_row(r4, a0, a1);
            acc_row(r5, e0, e1);
            acc_row(r6, a0, a1);
            acc_row(r7, e0, e1);
        }
        for (; j + 3 < end; j += 4) {
            int s0 = s.sorted[j], s1 = s.sorted[j + 1], s2 = s.sorted[j + 2], s3 = s.sorted[j + 3];
            uint4 r0 = ybf[(size_t)s0 * 8 + c];
            uint4 r1 = ybf[(size_t)s1 * 8 + c];
            uint4 r2 = ybf[(size_t)s2 * 8 + c];
            uint4 r3 = ybf[(size_t)s3 * 8 + c];
            acc_row(r0, a0, a1);
            acc_row(r1, e0, e1);
            acc_row(r2, a0, a1);
            acc_row(r3, e0, e1);
        }
        for (; j < end; ++j) {
            uint4 r = ybf[(size_t)s.sorted[j] * 8 + c];
            acc_row(r, a0, a1);
        }
        a0.x += e0.x; a0.y += e0.y; a0.z += e0.z; a0.w += e0.w;
        a1.x += e1.x; a1.y += e1.y; a1.z += e1.z; a1.w += e1.w;

        float dn = rsqrtf((float)(1 + cn));
        float4 bb0 = b4[2 * c];
        float4 bb1 = b4[2 * c + 1];
        float4 o0, o1;
        o0.x = fmaxf(fmaf(a0.x, dn, bb0.x), 0.f);
        o0.y = fmaxf(fmaf(a0.y, dn, bb0.y), 0.f);
        o0.z = fmaxf(fmaf(a0.z, dn, bb0.z), 0.f);
        o0.w = fmaxf(fmaf(a0.w, dn, bb0.w), 0.f);
        o1.x = fmaxf(fmaf(a1.x, dn, bb1.x), 0.f);
        o1.y = fmaxf(fmaf(a1.y, dn, bb1.y), 0.f);
        o1.z = fmaxf(fmaf(a1.z, dn, bb1.z), 0.f);
        o1.w = fmaxf(fmaf(a1.w, dn, bb1.w), 0.f);
        out4[(size_t)node * 16 + 2 * c] = o0;
        out4[(size_t)node * 16 + 2 * c + 1] = o1;
    }
}

// ================= cooperative mega-kernel =================
struct SMp {
    int hist[MAXBK]; int scanb[MAXBK]; int gbase[MAXBK];
    int stage[MTILE]; unsigned short bstage[MTILE];
};
struct SMg {
    float Wt[64 * 68]; float zt[16 * 68];
    int cnt[GBKT]; float dinvL[GBKT];
};
union SMu { SMp p; SMg g; SMb b; };

__global__ __launch_bounds__(256, 4) void mega2_k(
    const int* __restrict__ src, const int* __restrict__ dst,
    const float* __restrict__ z, const float* __restrict__ W,
    const float4* __restrict__ b4, ushort4* __restrict__ ybf,
    int* __restrict__ bcur, int* __restrict__ bp,
    float4* __restrict__ out4, int N, int E, int NBK, int nt)
{
    __shared__ SMu sm;
    cg::grid_group grid = cg::this_grid();
    int tid = threadIdx.x;
    int bid = blockIdx.x;
    int G = gridDim.x;

    // ---- P0: zero bcur ----
    for (int i = bid * 256 + tid; i < NBK; i += G * 256) bcur[i] = 0;
    grid.sync();

    // ---- P1: partition, grid-stride over tiles ----
    for (int t = bid; t < nt; t += G) {
        int tbase = t * MTILE;
        int n = E - tbase;
        if (n > MTILE) n = MTILE;
        __syncthreads();
        for (int i = tid; i < NBK; i += 256) sm.p.hist[i] = 0;
        __syncthreads();
        int pv[MEPT], pb[MEPT], pr[MEPT];
        int eb = tid * MEPT;
        bool full = (eb + MEPT <= n);
        if (full) {
            #pragma unroll
            for (int q = 0; q < MEPT / 4; ++q) {
                int4 s4 = *(const int4*)(src + tbase + eb + q * 4);
                int4 d4 = *(const int4*)(dst + tbase + eb + q * 4);
                int sa[4] = {s4.x, s4.y, s4.z, s4.w};
                int da[4] = {d4.x, d4.y, d4.z, d4.w};
                #pragma unroll
                for (int u = 0; u < 4; ++u) {
                    int e = q * 4 + u;
                    pv[e] = (sa[u] << BSH) | (da[u] & (GBKT - 1));
                    pb[e] = da[u] >> BSH;
                    pr[e] = atomicAdd(&sm.p.hist[pb[e]], 1);
                }
            }
        } else {
            #pragma unroll
            for (int e = 0; e < MEPT; ++e) {
                pb[e] = -1;
                if (eb + e < n) {
                    int s = src[tbase + eb + e];
                    int d = dst[tbase + eb + e];
                    pv[e] = (s << BSH) | (d & (GBKT - 1));
                    pb[e] = d >> BSH;
                    pr[e] = atomicAdd(&sm.p.hist[pb[e]], 1);
                }
            }
        }
        __syncthreads();
        if (tid < 64) {
            int run = 0;
            for (int base = 0; base < NBK; base += 64) {
                int i = base + tid;
                int orig = (i < NBK) ? sm.p.hist[i] : 0;
                int v = orig;
                #pragma unroll
                for (int off = 1; off < 64; off <<= 1) {
                    int t2 = __shfl_up(v, off, 64);
                    if (tid >= off) v += t2;
                }
                if (i < NBK) sm.p.scanb[i] = run + v - orig;
                run += __shfl(v, 63, 64);
            }
        }
        __syncthreads();
        for (int i = tid; i < NBK; i += 256)
            if (sm.p.hist[i]) sm.p.gbase[i] = i * CAP + atomicAdd(&bcur[i], sm.p.hist[i]);
        #pragma unroll
        for (int e = 0; e < MEPT; ++e) {
            if (pb[e] >= 0) {
                int p = sm.p.scanb[pb[e]] + pr[e];
                sm.p.stage[p] = pv[e];
                sm.p.bstage[p] = (unsigned short)pb[e];
            }
        }
        __syncthreads();
        for (int i = tid; i < n; i += 256) {
            int b = sm.p.bstage[i];
            bp[sm.p.gbase[b] + (i - sm.p.scanb[b])] = sm.p.stage[i];
        }
    }
    grid.sync();

    // ---- P2: degree + gemm per bucket, grid-stride ----
    for (int i = tid; i < DD * DD; i += 256) {
        int d = i >> 6, kk = i & 63;
        sm.g.Wt[kk * 68 + d] = W[i];
    }
    for (int k = bid; k < NBK; k += G) {
        __syncthreads();
        if (tid < GBKT) sm.g.cnt[tid] = 0;
        __syncthreads();
        {
            int ebeg = k * CAP;
            int eend = ebeg + bcur[k];
            for (int i = ebeg + tid; i < eend; i += 256)
                atomicAdd(&sm.g.cnt[bp[i] & (GBKT - 1)], 1);
        }
        __syncthreads();
        if (tid < GBKT) sm.g.dinvL[tid] = rsqrtf((float)(1 + sm.g.cnt[tid]));
        int base = k << BSH;
        for (int it = 0; it < 8; ++it) {     // 8 x 16-row sub-tiles
            __syncthreads();
            int rl = it * 16 + (tid >> 4);
            int row = base + rl;
            float4 v = (row < N) ? ((const float4*)z)[(size_t)row * 16 + (tid & 15)]
                                 : make_float4(0.f, 0.f, 0.f, 0.f);
            *(float4*)&sm.g.zt[(tid >> 4) * 68 + (tid & 15) * 4] = v;
            __syncthreads();
            int r = tid >> 4, c = tid & 15;
            float4 acc = make_float4(0.f, 0.f, 0.f, 0.f);
            #pragma unroll
            for (int kk = 0; kk < DD; ++kk) {
                float zv = sm.g.zt[r * 68 + kk];
                float4 w = *(const float4*)&sm.g.Wt[kk * 68 + c * 4];
                acc.x = fmaf(zv, w.x, acc.x);
                acc.y = fmaf(zv, w.y, acc.y);
                acc.z = fmaf(zv, w.z, acc.z);
                acc.w = fmaf(zv, w.w, acc.w);
            }
            if (row < N) {
                float s = sm.g.dinvL[rl];
                ushort4 o;
                o.x = f2bf(acc.x * s);
                o.y = f2bf(acc.y * s);
                o.z = f2bf(acc.z * s);
                o.w = f2bf(acc.w * s);
                ybf[(size_t)row * 16 + c] = o;
            }
        }
    }
    grid.sync();

    // ---- P3: sort + gather per bucket, grid-stride ----
    for (int k = bid; k < NBK; k += G) {
        __syncthreads();
        bg_body(sm.b, (const uint4*)ybf, bp, bcur[k], b4, out4, N, k);
    }
}

// ================= fallback kernels (R16 path) =================
__global__ __launch_bounds__(FPT) void part_k(const int* __restrict__ src,
                                              const int* __restrict__ dst,
                                              int* __restrict__ bcur,
                                              int* __restrict__ bp,
                                              int E, int NBK) {
    __shared__ int hist[MAXBK];
    __shared__ int scanb[MAXBK];
    __shared__ int gbase[MAXBK];
    __shared__ int stage[FTILE];
    __shared__ unsigned short bstage[FTILE];

    int tid = threadIdx.x;
    int tbase = blockIdx.x * FTILE;
    int n = E - tbase;
    if (n > FTILE) n = FTILE;

    for (int i = tid; i < NBK; i += FPT) hist[i] = 0;
    __syncthreads();

    int ss[FEPT], dd[FEPT];
    int eb = tid * FEPT;
    if (eb + FEPT <= n) {
        const int4* s4 = (const int4*)(src + tbase + eb);
        const int4* d4 = (const int4*)(dst + tbase + eb);
        int4 a = s4[0], b2 = s4[1], c4 = d4[0], e4 = d4[1];
        ss[0] = a.x; ss[1] = a.y; ss[2] = a.z; ss[3] = a.w;
        ss[4] = b2.x; ss[5] = b2.y; ss[6] = b2.z; ss[7] = b2.w;
        dd[0] = c4.x; dd[1] = c4.y; dd[2] = c4.z; dd[3] = c4.w;
        dd[4] = e4.x; dd[5] = e4.y; dd[6] = e4.z; dd[7] = e4.w;
    } else {
        #pragma unroll
        for (int e = 0; e < FEPT; ++e) {
            if (eb + e < n) { ss[e] = src[tbase + eb + e]; dd[e] = dst[tbase + eb + e]; }
            else dd[e] = -1;
        }
    }
    int pv[FEPT], pb[FEPT], pr[FEPT];
    #pragma unroll
    for (int e = 0; e < FEPT; ++e) {
        pb[e] = -1;
        if (eb + e < n && dd[e] >= 0) {
            pv[e] = (ss[e] << BSH) | (dd[e] & (GBKT - 1));
            pb[e] = dd[e] >> BSH;
            pr[e] = atomicAdd(&hist[pb[e]], 1);
        }
    }
    __syncthreads();

    if (tid < 64) {
        int run = 0;
        for (int base = 0; base < NBK; base += 64) {
            int i = base + tid;
            int orig = (i < NBK) ? hist[i] : 0;
            int v = orig;
            #pragma unroll
            for (int off = 1; off < 64; off <<= 1) {
                int t = __shfl_up(v, off, 64);
                if (tid >= off) v += t;
            }
            if (i < NBK) scanb[i] = run + v - orig;
            run += __shfl(v, 63, 64);
        }
    }
    __syncthreads();

    for (int i = tid; i < NBK; i += FPT)
        if (hist[i]) gbase[i] = i * CAP + atomicAdd(&bcur[i], hist[i]);
    #pragma unroll
    for (int e = 0; e < FEPT; ++e) {
        if (pb[e] >= 0) {
            int p = scanb[pb[e]] + pr[e];
            stage[p] = pv[e];
            bstage[p] = (unsigned short)pb[e];
        }
    }
    __syncthreads();

    for (int i = tid; i < n; i += FPT) {
        int b = bstage[i];
        bp[gbase[b] + (i - scanb[b])] = stage[i];
    }
}

__global__ __launch_bounds__(512) void dg_k(const int* __restrict__ bp,
                                            const int* __restrict__ bcur,
                                            const float* __restrict__ z,
                                            const float* __restrict__ W,
                                            ushort4* __restrict__ ybf, int N) {
    __shared__ float Wt[64 * 68];
    __shared__ float zt[32 * 68];
    __shared__ int cnt[GBKT];
    __shared__ float dinvL[GBKT];
    int k = blockIdx.x;
    int tid = threadIdx.x;
    int base = k << BSH;

    if (tid < GBKT) cnt[tid] = 0;
    for (int i = tid; i < DD * DD; i += 512) {
        int d = i >> 6, kk = i & 63;
        Wt[kk * 68 + d] = W[i];
    }
    __syncthreads();
    {
        int ebeg = k * CAP;
        int eend = ebeg + bcur[k];
        for (int i = ebeg + tid; i < eend; i += 512)
            atomicAdd(&cnt[bp[i] & (GBKT - 1)], 1);
    }
    __syncthreads();
    if (tid < GBKT) dinvL[tid] = rsqrtf((float)(1 + cnt[tid]));
    for (int it = 0; it < 4; ++it) {
        __syncthreads();
        int rl = it * 32 + (tid >> 4);
        int row = base + rl;
        float4 v = (row < N) ? ((const float4*)z)[(size_t)row * 16 + (tid & 15)]
                             : make_float4(0.f, 0.f, 0.f, 0.f);
        *(float4*)&zt[(tid >> 4) * 68 + (tid & 15) * 4] = v;
        __syncthreads();
        int r = tid >> 4, c = tid & 15;
        float4 acc = make_float4(0.f, 0.f, 0.f, 0.f);
        #pragma unroll
        for (int kk = 0; kk < DD; ++kk) {
            float zv = zt[r * 68 + kk];
            float4 w = *(const float4*)&Wt[kk * 68 + c * 4];
            acc.x = fmaf(zv, w.x, acc.x);
            acc.y = fmaf(zv, w.y, acc.y);
            acc.z = fmaf(zv, w.z, acc.z);
            acc.w = fmaf(zv, w.w, acc.w);
        }
        if (row < N) {
            float s = dinvL[rl];
            ushort4 o;
            o.x = f2bf(acc.x * s);
            o.y = f2bf(acc.y * s);
            o.z = f2bf(acc.z * s);
            o.w = f2bf(acc.w * s);
            ybf[(size_t)row * 16 + c] = o;
        }
    }
}

__global__ __launch_bounds__(256) void bg_k(const uint4* __restrict__ ybf,
                                            const int* __restrict__ bp,
                                            const int* __restrict__ bcur,
                                            const float4* __restrict__ b4,
                                            float4* __restrict__ out4, int N) {
    __shared__ SMb s;
    bg_body(s, ybf, bp, bcur[blockIdx.x], b4, out4, N, blockIdx.x);
}

// ================= launch =================
extern "C" void kernel_launch(void* const* d_in, const int* in_sizes, int n_in,
                              void* d_out, int out_size, void* d_ws, size_t ws_size,
                              hipStream_t stream) {
    const int* ei = (const int*)d_in[1];

    int N = in_sizes[0] / DD;
    int E = in_sizes[1] / 2;
    const int* src_p = ei;
    const int* dst_p = ei + E;
    const float* z_p = (const float*)d_in[0];
    const float* W_p = (const float*)d_in[2];
    const float4* b4_p = (const float4*)d_in[3];
    float4* out4_p = (float4*)d_out;

    int NBK = (N + GBKT - 1) >> BSH;
    int nt = (E + MTILE - 1) / MTILE;

    ushort4* ybf_p = (ushort4*)d_ws;                                   // 64N ushorts
    int* bcur_p = (int*)((unsigned short*)d_ws + (size_t)64 * N);      // NBK (counts)
    int* bp_p = bcur_p + NBK;                                          // NBK*CAP

    // try cooperative mega-kernel
    bool coop_ok = false;
    if (NBK <= MAXBK) {
        int dev = 0;
        hipGetDevice(&dev);
        hipDeviceProp_t prop;
        int mbpc = 0;
        if (hipGetDeviceProperties(&prop, dev) == hipSuccess &&
            hipOccupancyMaxActiveBlocksPerMultiprocessor(&mbpc, mega2_k, 256, 0) == hipSuccess &&
            mbpc > 0) {
            long long cap = (long long)mbpc * prop.multiProcessorCount;
            int G = (NBK > nt) ? NBK : nt;
            if (G > cap) G = (int)cap;
            if (G > 0) {
                void* args[] = {
                    (void*)&src_p, (void*)&dst_p, (void*)&z_p, (void*)&W_p, (void*)&b4_p,
                    (void*)&ybf_p, (void*)&bcur_p, (void*)&bp_p, (void*)&out4_p,
                    (void*)&N, (void*)&E, (void*)&NBK, (void*)&nt
                };
                hipError_t ce = hipLaunchCooperativeKernel((void*)mega2_k, dim3(G), dim3(256),
                                                           args, 0, stream);
                coop_ok = (ce == hipSuccess);
            }
        }
    }

    if (!coop_ok) {
        // fallback: proven 3-kernel path (R16)
        hipMemsetAsync(bcur_p, 0, sizeof(int) * NBK, stream);
        part_k<<<(E + FTILE - 1) / FTILE, FPT, 0, stream>>>(src_p, dst_p, bcur_p, bp_p, E, NBK);
        dg_k<<<NBK, 512, 0, stream>>>(bp_p, bcur_p, z_p, W_p, ybf_p, N);
        bg_k<<<NBK, 256, 0, stream>>>((const uint4*)ybf_p, bp_p, bcur_p, b4_p, out4_p, N);
    }
}

// Round 18
// 86.955 us; speedup vs baseline: 3.2937x; 3.2937x over previous
//
#include <hip/hip_runtime.h>

#define DD 64
#define BSH 7                   // 128 nodes per bucket
#define GBKT 128
#define CAP 2560                // = 10*256; mean fill 2046, +11 sigma
#define TILE 8192               // edges per partition tile
#define PTHREADS 1024
#define EPT 8                   // TILE/PTHREADS
#define MAXBK 1024              // >= NBK

__device__ __forceinline__ float bflo(unsigned int u) {
    return __uint_as_float(u << 16);
}
__device__ __forceinline__ float bfhi(unsigned int u) {
    return __uint_as_float(u & 0xffff0000u);
}
__device__ __forceinline__ unsigned short f2bf(float f) {   // RNE
    unsigned int b = __float_as_uint(f);
    return (unsigned short)((b + 0x7fffu + ((b >> 16) & 1u)) >> 16);
}
__device__ __forceinline__ void acc_row(uint4 r, float4& lo, float4& hi) {
    lo.x += bflo(r.x); lo.y += bfhi(r.x);
    lo.z += bflo(r.y); lo.w += bfhi(r.y);
    hi.x += bflo(r.z); hi.y += bfhi(r.z);
    hi.z += bflo(r.w); hi.w += bfhi(r.w);
}

// ---------------- bucketed partition; bcur holds per-bucket COUNTS (memset 0) ----------------
// packed = (src << BSH) | (dst & (GBKT-1))
__global__ __launch_bounds__(PTHREADS) void part_k(const int* __restrict__ src,
                                                   const int* __restrict__ dst,
                                                   int* __restrict__ bcur,
                                                   int* __restrict__ bp,
                                                   int E, int NBK) {
    __shared__ int hist[MAXBK];
    __shared__ int scanb[MAXBK];
    __shared__ int gbase[MAXBK];
    __shared__ int stage[TILE];             // 32 KB packed
    __shared__ unsigned short bstage[TILE]; // 16 KB bucket ids

    int tid = threadIdx.x;
    int tbase = blockIdx.x * TILE;
    int n = E - tbase;
    if (n > TILE) n = TILE;

    for (int i = tid; i < NBK; i += PTHREADS) hist[i] = 0;
    __syncthreads();

    // 8 consecutive edges per thread (int4 x2 when aligned & full)
    int ss[EPT], dd[EPT];
    int eb = tid * EPT;                     // within tile
    bool dal = ((reinterpret_cast<size_t>(dst) & 15) == 0);
    if (dal && eb + EPT <= n) {
        const int4* s4 = (const int4*)(src + tbase + eb);
        const int4* d4 = (const int4*)(dst + tbase + eb);
        int4 a = s4[0], b2 = s4[1], c4 = d4[0], e4 = d4[1];
        ss[0] = a.x; ss[1] = a.y; ss[2] = a.z; ss[3] = a.w;
        ss[4] = b2.x; ss[5] = b2.y; ss[6] = b2.z; ss[7] = b2.w;
        dd[0] = c4.x; dd[1] = c4.y; dd[2] = c4.z; dd[3] = c4.w;
        dd[4] = e4.x; dd[5] = e4.y; dd[6] = e4.z; dd[7] = e4.w;
    } else {
        #pragma unroll
        for (int e = 0; e < EPT; ++e) {
            if (eb + e < n) { ss[e] = src[tbase + eb + e]; dd[e] = dst[tbase + eb + e]; }
            else dd[e] = -1;
        }
    }
    // single atomic pass: rank within (tile, bucket)
    int pv[EPT], pb[EPT], pr[EPT];
    #pragma unroll
    for (int e = 0; e < EPT; ++e) {
        pb[e] = -1;
        if (eb + e < n && dd[e] >= 0) {
            pv[e] = (ss[e] << BSH) | (dd[e] & (GBKT - 1));
            pb[e] = dd[e] >> BSH;
            pr[e] = atomicAdd(&hist[pb[e]], 1);
        }
    }
    __syncthreads();

    // one-wave chunked exclusive scan of hist -> scanb
    if (tid < 64) {
        int run = 0;
        for (int base = 0; base < NBK; base += 64) {
            int i = base + tid;
            int orig = (i < NBK) ? hist[i] : 0;
            int v = orig;
            #pragma unroll
            for (int off = 1; off < 64; off <<= 1) {
                int t = __shfl_up(v, off, 64);
                if (tid >= off) v += t;
            }
            if (i < NBK) scanb[i] = run + v - orig;
            run += __shfl(v, 63, 64);
        }
    }
    __syncthreads();

    // reserve global ranges (bcur = counts) and place staged edges
    for (int i = tid; i < NBK; i += PTHREADS)
        if (hist[i]) gbase[i] = i * CAP + atomicAdd(&bcur[i], hist[i]);
    #pragma unroll
    for (int e = 0; e < EPT; ++e) {
        if (pb[e] >= 0) {
            int p = scanb[pb[e]] + pr[e];
            stage[p] = pv[e];
            bstage[p] = (unsigned short)pb[e];
        }
    }
    __syncthreads();

    // contiguous runs per bucket
    for (int i = tid; i < n; i += PTHREADS) {
        int b = bstage[i];
        bp[gbase[b] + (i - scanb[b])] = stage[i];
    }
}

// ---------------- fused per-bucket degree + gemm: y = bf16((z @ W^T) * dinv) ----------------
// one block (512 thr) per 128-node bucket; dinv never leaves the block.
__global__ __launch_bounds__(512) void dg_k(const int* __restrict__ bp,
                                            const int* __restrict__ bcur,
                                            const float* __restrict__ z,
                                            const float* __restrict__ W,
                                            ushort4* __restrict__ ybf, int N) {
    __shared__ float Wt[64 * 68];    // 17.4 KB
    __shared__ float zt[32 * 68];    // 8.7 KB
    __shared__ int cnt[GBKT];
    __shared__ float dinvL[GBKT];
    int k = blockIdx.x;
    int tid = threadIdx.x;
    int base = k << BSH;

    if (tid < GBKT) cnt[tid] = 0;
    // stage W^T (independent of histogram)
    for (int i = tid; i < DD * DD; i += 512) {
        int d = i >> 6, kk = i & 63;
        Wt[kk * 68 + d] = W[i];
    }
    __syncthreads();
    {
        int ebeg = k * CAP;
        int eend = ebeg + bcur[k];
        for (int i = ebeg + tid; i < eend; i += 512)
            atomicAdd(&cnt[bp[i] & (GBKT - 1)], 1);
    }
    __syncthreads();
    if (tid < GBKT) dinvL[tid] = rsqrtf((float)(1 + cnt[tid]));
    // 4 x 32-row gemm sub-tiles
    for (int it = 0; it < 4; ++it) {
        __syncthreads();   // dinvL ready (it==0) / previous zt consumed
        int rl = it * 32 + (tid >> 4);           // local row 0..127
        int row = base + rl;
        float4 v = (row < N) ? ((const float4*)z)[(size_t)row * 16 + (tid & 15)]
                             : make_float4(0.f, 0.f, 0.f, 0.f);
        *(float4*)&zt[(tid >> 4) * 68 + (tid & 15) * 4] = v;
        __syncthreads();
        int r = tid >> 4, c = tid & 15;
        float4 acc = make_float4(0.f, 0.f, 0.f, 0.f);
        #pragma unroll
        for (int kk = 0; kk < DD; ++kk) {
            float zv = zt[r * 68 + kk];
            float4 w = *(const float4*)&Wt[kk * 68 + c * 4];
            acc.x = fmaf(zv, w.x, acc.x);
            acc.y = fmaf(zv, w.y, acc.y);
            acc.z = fmaf(zv, w.z, acc.z);
            acc.w = fmaf(zv, w.w, acc.w);
        }
        if (row < N) {
            float s = dinvL[rl];
            ushort4 o;
            o.x = f2bf(acc.x * s);
            o.y = f2bf(acc.y * s);
            o.z = f2bf(acc.z * s);
            o.w = f2bf(acc.w * s);
            ybf[(size_t)row * 16 + c] = o;
        }
    }
}

// ---------------- fused per-bucket sort (single reg-cached bp pass) + gather ----------------
__global__ __launch_bounds__(256) void bg_k(const uint4* __restrict__ ybf,
                                            const int* __restrict__ bp,
                                            const int* __restrict__ bcur,
                                            const float4* __restrict__ b4,
                                            float4* __restrict__ out4, int N) {
    __shared__ int cnt[GBKT];
    __shared__ int excl[GBKT];
    __shared__ int cur[GBKT];
    __shared__ int sorted[CAP];   // 10 KB
    __shared__ int nextn;
    int k = blockIdx.x;
    int tid = threadIdx.x;
    int ebeg = k * CAP;
    int eend = ebeg + bcur[k];
    int base = k << BSH;

    if (tid < GBKT) cnt[tid] = 0;
    if (tid == 0) nextn = 0;
    __syncthreads();
    // single bp read, cached in registers (CAP == 10*256)
    int ev[10];
    #pragma unroll
    for (int u = 0; u < 10; ++u) {
        int i = ebeg + tid + u * 256;
        ev[u] = (i < eend) ? bp[i] : -1;
    }
    #pragma unroll
    for (int u = 0; u < 10; ++u)
        if (ev[u] >= 0) atomicAdd(&cnt[ev[u] & (GBKT - 1)], 1);
    __syncthreads();

    // 128-wide ladder scan (inclusive) -> exclusive
    if (tid < GBKT) excl[tid] = cnt[tid];
    __syncthreads();
    #pragma unroll
    for (int off = 1; off < GBKT; off <<= 1) {
        int t = (tid < GBKT && tid >= off) ? excl[tid - off] : 0;
        __syncthreads();
        if (tid < GBKT) excl[tid] += t;
        __syncthreads();
    }
    if (tid < GBKT) {
        excl[tid] -= cnt[tid];
        cur[tid] = excl[tid];
    }
    __syncthreads();

    #pragma unroll
    for (int u = 0; u < 10; ++u)
        if (ev[u] >= 0) {
            int l = ev[u] & (GBKT - 1);
            int pos = atomicAdd(&cur[l], 1);
            sorted[pos] = ev[u] >> BSH;
        }
    __syncthreads();

    // gather: 8-lane groups pull node slots dynamically
    int lane = tid & 63;
    int c = tid & 7;            // col block (8 bf16 cols = 16B)
    for (;;) {
        int slot;
        if ((tid & 7) == 0) slot = atomicAdd(&nextn, 1);
        slot = __shfl(slot, lane & 56, 64);
        if (slot >= GBKT) break;
        int node = base + slot;
        if (node >= N) continue;
        int beg = excl[slot];
        int cn = cnt[slot];
        int end = beg + cn;
        // self-loop message seeds accumulator set A
        uint4 v = ybf[(size_t)node * 8 + c];
        float4 a0 = make_float4(bflo(v.x), bfhi(v.x), bflo(v.y), bfhi(v.y));
        float4 a1 = make_float4(bflo(v.z), bfhi(v.z), bflo(v.w), bfhi(v.w));
        float4 e0 = make_float4(0.f, 0.f, 0.f, 0.f);
        float4 e1 = e0;
        int j = beg;
        for (; j + 7 < end; j += 8) {   // 8-deep pipeline
            int s0 = sorted[j],     s1 = sorted[j + 1], s2 = sorted[j + 2], s3 = sorted[j + 3];
            int s4 = sorted[j + 4], s5 = sorted[j + 5], s6 = sorted[j + 6], s7 = sorted[j + 7];
            uint4 r0 = ybf[(size_t)s0 * 8 + c];
            uint4 r1 = ybf[(size_t)s1 * 8 + c];
            uint4 r2 = ybf[(size_t)s2 * 8 + c];
            uint4 r3 = ybf[(size_t)s3 * 8 + c];
            uint4 r4 = ybf[(size_t)s4 * 8 + c];
            uint4 r5 = ybf[(size_t)s5 * 8 + c];
            uint4 r6 = ybf[(size_t)s6 * 8 + c];
            uint4 r7 = ybf[(size_t)s7 * 8 + c];
            acc_row(r0, a0, a1);
            acc_row(r1, e0, e1);
            acc_row(r2, a0, a1);
            acc_row(r3, e0, e1);
            acc_row(r4, a0, a1);
            acc_row(r5, e0, e1);
            acc_row(r6, a0, a1);
            acc_row(r7, e0, e1);
        }
        for (; j + 3 < end; j += 4) {
            int s0 = sorted[j], s1 = sorted[j + 1], s2 = sorted[j + 2], s3 = sorted[j + 3];
            uint4 r0 = ybf[(size_t)s0 * 8 + c];
            uint4 r1 = ybf[(size_t)s1 * 8 + c];
            uint4 r2 = ybf[(size_t)s2 * 8 + c];
            uint4 r3 = ybf[(size_t)s3 * 8 + c];
            acc_row(r0, a0, a1);
            acc_row(r1, e0, e1);
            acc_row(r2, a0, a1);
            acc_row(r3, e0, e1);
        }
        for (; j < end; ++j) {
            uint4 r = ybf[(size_t)sorted[j] * 8 + c];
            acc_row(r, a0, a1);
        }
        a0.x += e0.x; a0.y += e0.y; a0.z += e0.z; a0.w += e0.w;
        a1.x += e1.x; a1.y += e1.y; a1.z += e1.z; a1.w += e1.w;

        float dn = rsqrtf((float)(1 + cn));
        float4 bb0 = b4[2 * c];
        float4 bb1 = b4[2 * c + 1];
        float4 o0, o1;
        o0.x = fmaxf(fmaf(a0.x, dn, bb0.x), 0.f);
        o0.y = fmaxf(fmaf(a0.y, dn, bb0.y), 0.f);
        o0.z = fmaxf(fmaf(a0.z, dn, bb0.z), 0.f);
        o0.w = fmaxf(fmaf(a0.w, dn, bb0.w), 0.f);
        o1.x = fmaxf(fmaf(a1.x, dn, bb1.x), 0.f);
        o1.y = fmaxf(fmaf(a1.y, dn, bb1.y), 0.f);
        o1.z = fmaxf(fmaf(a1.z, dn, bb1.z), 0.f);
        o1.w = fmaxf(fmaf(a1.w, dn, bb1.w), 0.f);
        out4[(size_t)node * 16 + 2 * c] = o0;
        out4[(size_t)node * 16 + 2 * c + 1] = o1;
    }
}

// ---------------- launch ----------------

extern "C" void kernel_launch(void* const* d_in, const int* in_sizes, int n_in,
                              void* d_out, int out_size, void* d_ws, size_t ws_size,
                              hipStream_t stream) {
    const float* z = (const float*)d_in[0];
    const int* ei  = (const int*)d_in[1];
    const float* W = (const float*)d_in[2];
    const float* b = (const float*)d_in[3];
    float* out = (float*)d_out;

    const int N = in_sizes[0] / DD;
    const int E = in_sizes[1] / 2;
    const int* src = ei;
    const int* dst = ei + E;

    const int NBK = (N + GBKT - 1) >> BSH;

    // workspace layout
    unsigned short* ybf = (unsigned short*)d_ws;      // 64N ushorts (bf16)
    int*   bcur  = (int*)(ybf + (size_t)64 * N);      // NBK (counts)
    int*   bp    = bcur + NBK;                        // NBK*CAP

    hipMemsetAsync(bcur, 0, sizeof(int) * NBK, stream);
    part_k<<<(E + TILE - 1) / TILE, PTHREADS, 0, stream>>>(src, dst, bcur, bp, E, NBK);
    dg_k<<<NBK, 512, 0, stream>>>(bp, bcur, z, W, (ushort4*)ybf, N);
    bg_k<<<NBK, 256, 0, stream>>>((const uint4*)ybf, bp, bcur,
                                  (const float4*)b, (float4*)out, N);
}